// Round 2
// baseline (1123.909 us; speedup 1.0000x reference)
//
#include <hip/hip_runtime.h>

// ---------------------------------------------------------------------------
// Decoder: fused cvt -> fused h0/c0 init GEMM -> gx GEMM -> 32 per-step
// launches where each step block ALSO computes its 40-col vocab slab of
// out[t-1] = sigmoid(h_t @ W_fc^T + b_fc) in-block after the cell math
// (no extra blocks: round-1 lesson -- step kernel is 1 block/CU by VGPR,
// so extra FC blocks serialized AFTER the step, +7.6us/step).
// Tail FC for h_32 via mfma_gemm128.
// ---------------------------------------------------------------------------

#define B_  64
#define T_  32
#define E_  512
#define H_  1024
#define V_  10000
#define F_  2048

typedef short short8 __attribute__((ext_vector_type(8)));
typedef float floatx4 __attribute__((ext_vector_type(4)));

__device__ __forceinline__ float bf2f(unsigned short u) {
  union { unsigned int i; float f; } c; c.i = ((unsigned int)u) << 16; return c.f;
}
__device__ __forceinline__ unsigned short f2bf(float f) {
  union { float f; unsigned int i; } c; c.f = f;
  unsigned int x = c.i;
  return (unsigned short)((x + 0x7fffu + ((x >> 16) & 1u)) >> 16);
}
__device__ __forceinline__ float sigmoidf_(float x) {
  return 1.0f / (1.0f + __expf(-x));
}
// async global->LDS, 16B per lane. LDS dest must be linear in lane (16B/lane).
__device__ __forceinline__ void gl_lds16(const unsigned short* g, unsigned short* l) {
  __builtin_amdgcn_global_load_lds(
      (const __attribute__((address_space(1))) unsigned int*)g,
      (__attribute__((address_space(3))) unsigned int*)l, 16, 0, 0);
}
// bijective XCD-chunked block remap (m204 formula; identity when nwg < 8)
__device__ __forceinline__ int xcd_swz(int lin, int nwg) {
  if (nwg < 8) return lin;
  int q = nwg >> 3, r = nwg & 7;
  int xcd = lin & 7, pos = lin >> 3;
  return (xcd < r ? xcd * (q + 1) : r * (q + 1) + (xcd - r) * q) + pos;
}

// ---------------- fused fp32 -> bf16 convert for all 6 arrays --------------
#define C_WIH  524288    // 4H*E/4
#define C_WHH  1048576   // 4H*H/4
#define C_WFC  2560000   // V*H/4
#define C_WI0  524288    // H*F/4
#define C_WC0  524288
#define C_FEA  32768     // B*F/4
#define C_TOT  (C_WIH + C_WHH + C_WFC + C_WI0 + C_WC0 + C_FEA)

__global__ __launch_bounds__(256) void cvt_all(
    const float* __restrict__ s0, const float* __restrict__ s1,
    const float* __restrict__ s2, const float* __restrict__ s3,
    const float* __restrict__ s4, const float* __restrict__ s5,
    unsigned short* __restrict__ d0, unsigned short* __restrict__ d1,
    unsigned short* __restrict__ d2, unsigned short* __restrict__ d3,
    unsigned short* __restrict__ d4, unsigned short* __restrict__ d5) {
  int i = blockIdx.x * blockDim.x + threadIdx.x;
  int stride = gridDim.x * blockDim.x;
  for (; i < C_TOT; i += stride) {
    const float* s; unsigned short* d; int j = i;
    if (j < C_WIH)            { s = s0; d = d0; }
    else if ((j -= C_WIH) < C_WHH) { s = s1; d = d1; }
    else if ((j -= C_WHH) < C_WFC) { s = s2; d = d2; }
    else if ((j -= C_WFC) < C_WI0) { s = s3; d = d3; }
    else if ((j -= C_WI0) < C_WC0) { s = s4; d = d4; }
    else { j -= C_WC0; s = s5; d = d5; }
    float4 v = ((const float4*)s)[j];
    ushort4 o;
    o.x = f2bf(v.x); o.y = f2bf(v.y); o.z = f2bf(v.z); o.w = f2bf(v.w);
    ((ushort4*)d)[j] = o;
  }
}

// ---------------- embedding gather -> bf16, rows ordered (t*64+b) ----------
__global__ __launch_bounds__(128) void embed_gather(
    const float* __restrict__ table, const int* __restrict__ captions,
    unsigned short* __restrict__ out) {
  int row = blockIdx.x;            // row = t*B + b
  int t = row >> 6, b = row & 63;
  int idx = captions[b * T_ + t];
  const float4* src = (const float4*)(table + (size_t)idx * E_);
  ushort4* dst = (ushort4*)(out + (size_t)row * E_);
  for (int e = threadIdx.x; e < E_ / 4; e += blockDim.x) {
    float4 v = src[e];
    ushort4 o;
    o.x = f2bf(v.x); o.y = f2bf(v.y); o.z = f2bf(v.z); o.w = f2bf(v.w);
    dst[e] = o;
  }
}

// ---------------- 128x128 LDS-staged bf16 MFMA GEMM ------------------------
// C = act(A @ W^T + bias).  2-phase double-buffer: stage(next) issued before
// compute(cur); single barrier per K-iter (syncthreads drains vmcnt).
// XOR bank swizzle: LDS row of 32 shorts, 16B slot s holds global chunk
// s^(row&3) (global side permuted; LDS stays lane-linear for gl_lds).
// OUT_INIT: N=2048 fused h0|c0 -> out (bf16, stride H_) / out2 (f32).
template <int ACT_SIGMOID, int OUT_BF16, int OUT_INIT>
__global__ __launch_bounds__(256) void mfma_gemm128(
    const unsigned short* __restrict__ A, const unsigned short* __restrict__ W,
    const float* __restrict__ bias1, const float* __restrict__ bias2,
    void* __restrict__ out, void* __restrict__ out2, int M, int N, int K) {
  __shared__ unsigned short At[2][128 * 32];   // 16 KB
  __shared__ unsigned short Wt[2][128 * 32];   // 16 KB

  const int tid  = threadIdx.x;
  const int lane = tid & 63;
  const int wave = tid >> 6;
  const int l15  = lane & 15;
  const int quad = lane >> 4;
  const int wm   = (wave >> 1) * 64;
  const int wn   = (wave & 1) * 64;

  const int gx  = gridDim.x;
  const int nwg = gx * gridDim.y;
  const int wg  = xcd_swz(blockIdx.y * gx + blockIdx.x, nwg);
  const int m0  = (wg % gx) * 128;
  const int n0  = (wg / gx) * 128;
  const int ksl = (quad ^ (l15 & 3)) * 8;  // swizzled k-chunk for frag reads

  const int c0i = tid, c1i = tid + 256;
  const int ar0 = c0i >> 2, ak0 = (((c0i & 3) ^ (ar0 & 3)) * 8);
  const int ar1 = c1i >> 2, ak1 = (((c1i & 3) ^ (ar1 & 3)) * 8);
  int am0 = m0 + ar0; if (am0 > M - 1) am0 = M - 1;
  int am1 = m0 + ar1; if (am1 > M - 1) am1 = M - 1;
  int wn0 = n0 + ar0; if (wn0 > N - 1) wn0 = N - 1;
  int wn1 = n0 + ar1; if (wn1 > N - 1) wn1 = N - 1;
  const unsigned short* Ag0 = A + (size_t)am0 * K + ak0;
  const unsigned short* Ag1 = A + (size_t)am1 * K + ak1;
  const unsigned short* Wg0 = W + (size_t)wn0 * K + ak0;
  const unsigned short* Wg1 = W + (size_t)wn1 * K + ak1;

  floatx4 acc[4][4];
#pragma unroll
  for (int i = 0; i < 4; ++i)
#pragma unroll
    for (int j = 0; j < 4; ++j) acc[i][j] = (floatx4){0.f, 0.f, 0.f, 0.f};

  // prologue stage of k-tile 0 into buffer 0
  gl_lds16(Ag0, &At[0][c0i * 8]);
  gl_lds16(Ag1, &At[0][c1i * 8]);
  gl_lds16(Wg0, &Wt[0][c0i * 8]);
  gl_lds16(Wg1, &Wt[0][c1i * 8]);
  __syncthreads();

  int cur = 0;
  for (int k0 = 0; k0 < K; k0 += 32) {
    const int kn = k0 + 32;
    if (kn < K) {                      // issue next tile before compute
      const int nb = cur ^ 1;
      gl_lds16(Ag0 + kn, &At[nb][c0i * 8]);
      gl_lds16(Ag1 + kn, &At[nb][c1i * 8]);
      gl_lds16(Wg0 + kn, &Wt[nb][c0i * 8]);
      gl_lds16(Wg1 + kn, &Wt[nb][c1i * 8]);
    }
    short8 a[4], b[4];
#pragma unroll
    for (int mt = 0; mt < 4; ++mt)
      a[mt] = *(const short8*)&At[cur][(wm + mt * 16 + l15) * 32 + ksl];
#pragma unroll
    for (int nt = 0; nt < 4; ++nt)
      b[nt] = *(const short8*)&Wt[cur][(wn + nt * 16 + l15) * 32 + ksl];
#pragma unroll
    for (int mt = 0; mt < 4; ++mt)
#pragma unroll
      for (int nt = 0; nt < 4; ++nt)
        acc[mt][nt] = __builtin_amdgcn_mfma_f32_16x16x32_bf16(a[mt], b[nt], acc[mt][nt], 0, 0, 0);
    __syncthreads();                   // drains vmcnt: next tile resident
    cur ^= 1;
  }

#pragma unroll
  for (int nt = 0; nt < 4; ++nt) {
    int col = n0 + wn + nt * 16 + l15;
    if (col >= N) continue;
    float bsum;
    if (OUT_INIT)
      bsum = (col < H_) ? bias1[col] : bias2[col - H_];
    else
      bsum = (bias1 ? bias1[col] : 0.f) + (bias2 ? bias2[col] : 0.f);
#pragma unroll
    for (int mt = 0; mt < 4; ++mt) {
#pragma unroll
      for (int r = 0; r < 4; ++r) {
        int m = m0 + wm + mt * 16 + quad * 4 + r;
        if (m >= M) continue;
        float v = acc[mt][nt][r] + bsum;
        if (ACT_SIGMOID) v = sigmoidf_(v);
        if (OUT_INIT) {
          if (col < H_)
            ((unsigned short*)out)[(size_t)m * H_ + col] = f2bf(v);
          else
            ((float*)out2)[(size_t)m * H_ + (col - H_)] = v;
        } else if (OUT_BF16) {
          ((unsigned short*)out)[(size_t)m * N + col] = f2bf(v);
        } else {
          ((float*)out)[(size_t)m * N + col] = v;
        }
      }
    }
  }
}

// ---------------- per-step LSTM kernel + in-block FC piggyback -------------
// Grid 256 blocks x 512 thr (1 block/CU). Step part = round-0 structure.
// After cell math, the SAME block computes its 40-col vocab slab of
// out_row = sigmoid(h_in @ W_fc^T + b_fc) -- h_in (=h_t) is this launch's
// own input, W_fc slab (80KB/block) is L2-resident across steps.
// No LDS, no barriers, no extra blocks.
#define WSPAD 1032   // 1024 + 8 bf16 pad per row (stride 516 dwords: 2-way)
__global__ __launch_bounds__(512, 2) void lstm_step(
    const unsigned short* __restrict__ W_hh_b,  // [4H,H] bf16
    const unsigned short* __restrict__ gx_t,    // [B,4H] bf16 (x-part+biases)
    float* __restrict__ c,                      // [B,H] f32, in-place
    const unsigned short* __restrict__ h_in,    // [B,H] bf16 (= h_t)
    unsigned short* __restrict__ h_out,         // [B,H] bf16 (= h_{t+1})
    const unsigned short* __restrict__ W_fc_b,  // [V,H] bf16
    const float* __restrict__ b_fc,             // [V] f32
    float* __restrict__ fc_out) {               // out rows for h_t, or null
  __shared__ unsigned short Ws[16 * WSPAD];     // ~33 KB
  __shared__ float gbuf[2][B_][17];             // ~8.7 KB

  const int tid  = threadIdx.x;
  const int lane = tid & 63;
  const int wave = tid >> 6;        // 0..7
  const int l15  = lane & 15;
  const int quad = lane >> 4;
  const int kb   = quad * 8;
  const int kh   = wave >> 2;       // K half: [kh*512, kh*512+512)
  const int mt   = wave & 3;        // batch tile: batches mt*16..+15
  const int colbase = blockIdx.x * 4;

  // ---- async-stage 16 W_hh rows into LDS (gate-major: row n <-> W_hh row
  // (n>>2)*H + colbase + (n&3)); each wave writes contiguous 1KB half-rows --
#pragma unroll
  for (int it = 0; it < 4; ++it) {
    int row  = it * 4 + (wave >> 1);
    int half = wave & 1;
    int grow = (row >> 2) * H_ + colbase + (row & 3);
    gl_lds16(W_hh_b + (size_t)grow * H_ + half * 512 + lane * 8,
             &Ws[row * WSPAD + half * 512]);
  }

  // ---- prefetch h fragment (16 x 16B) into registers (overlaps staging) ---
  const unsigned short* hp = h_in + (size_t)(mt * 16 + l15) * H_ + kh * 512 + kb;
  short8 hx[16];
#pragma unroll
  for (int i = 0; i < 16; ++i)
    hx[i] = *(const short8*)(hp + i * 32);

  // ---- prefetch cell inputs (waves 0-3 only; wave-uniform branch) ---------
  const int cb = tid >> 2, cj = tid & 3;
  float gxi = 0.f, gxf = 0.f, gxg = 0.f, gxo = 0.f, c_old = 0.f;
  if (tid < 256) {
    const unsigned short* gxp = gx_t + (size_t)cb * (4 * H_) + colbase + cj;
    gxi = bf2f(gxp[0 * H_]);
    gxf = bf2f(gxp[1 * H_]);
    gxg = bf2f(gxp[2 * H_]);
    gxo = bf2f(gxp[3 * H_]);
    c_old = c[cb * H_ + colbase + cj];
  }

  __syncthreads();   // drains vmcnt: staging + prefetches complete

  floatx4 a0 = (floatx4){0,0,0,0}, a1 = a0, a2 = a0, a3 = a0;
#pragma unroll
  for (int i = 0; i < 16; i += 4) {
    short8 w0 = *(const short8*)&Ws[l15 * WSPAD + kh * 512 + kb + (i + 0) * 32];
    short8 w1 = *(const short8*)&Ws[l15 * WSPAD + kh * 512 + kb + (i + 1) * 32];
    short8 w2 = *(const short8*)&Ws[l15 * WSPAD + kh * 512 + kb + (i + 2) * 32];
    short8 w3 = *(const short8*)&Ws[l15 * WSPAD + kh * 512 + kb + (i + 3) * 32];
    a0 = __builtin_amdgcn_mfma_f32_16x16x32_bf16(hx[i + 0], w0, a0, 0, 0, 0);
    a1 = __builtin_amdgcn_mfma_f32_16x16x32_bf16(hx[i + 1], w1, a1, 0, 0, 0);
    a2 = __builtin_amdgcn_mfma_f32_16x16x32_bf16(hx[i + 2], w2, a2, 0, 0, 0);
    a3 = __builtin_amdgcn_mfma_f32_16x16x32_bf16(hx[i + 3], w3, a3, 0, 0, 0);
  }
  floatx4 acc = (a0 + a1) + (a2 + a3);

#pragma unroll
  for (int r = 0; r < 4; ++r)
    gbuf[kh][mt * 16 + quad * 4 + r][l15] = acc[r];
  __syncthreads();

  // ---- cell math: thread owns (batch cb, col colbase+cj); waves 0-3 -------
  if (tid < 256) {
    float gi = gbuf[0][cb][0  + cj] + gbuf[1][cb][0  + cj] + gxi;
    float gf = gbuf[0][cb][4  + cj] + gbuf[1][cb][4  + cj] + gxf;
    float gg = gbuf[0][cb][8  + cj] + gbuf[1][cb][8  + cj] + gxg;
    float go = gbuf[0][cb][12 + cj] + gbuf[1][cb][12 + cj] + gxo;
    gi = sigmoidf_(gi);
    gf = sigmoidf_(gf);
    gg = tanhf(gg);
    go = sigmoidf_(go);
    int ci = cb * H_ + colbase + cj;
    float cn = gf * c_old + gi * gg;
    c[ci] = cn;
    h_out[ci] = f2bf(go * tanhf(cn));
  }

  // ---- in-block FC piggyback: block covers vocab cols [vb, vb+40) ---------
  // 12 MFMA tiles = 4 batch-frags x 3 col-frags (48 cols, last 8 discarded).
  // Cell-math waves (0-3) take 1 tile (cf=0); waves 4-7 take 2 (cf=1,2).
  if (fc_out != nullptr) {
    const int vb = blockIdx.x * 40;
    if (vb < V_) {
      const int bf = wave & 3;
      const unsigned short* Ap = h_in + (size_t)(bf * 16 + l15) * H_ + kb;
      const int two = (wave >= 4);
      const int cf0 = two ? 1 : 0;
      const int col0 = vb + (cf0 + 0) * 16 + l15;
      const int col1 = vb + (cf0 + 1) * 16 + l15;   // only if two
      const int r0 = col0 < V_ ? col0 : V_ - 1;
      const int r1 = col1 < V_ ? col1 : V_ - 1;
      const unsigned short* Bp0 = W_fc_b + (size_t)r0 * H_ + kb;
      const unsigned short* Bp1 = W_fc_b + (size_t)r1 * H_ + kb;
      floatx4 f0 = (floatx4){0.f, 0.f, 0.f, 0.f}, f1 = f0;
      if (two) {
#pragma unroll 4
        for (int k = 0; k < H_; k += 32) {
          short8 af = *(const short8*)(Ap + k);
          short8 b0 = *(const short8*)(Bp0 + k);
          short8 b1 = *(const short8*)(Bp1 + k);
          f0 = __builtin_amdgcn_mfma_f32_16x16x32_bf16(af, b0, f0, 0, 0, 0);
          f1 = __builtin_amdgcn_mfma_f32_16x16x32_bf16(af, b1, f1, 0, 0, 0);
        }
      } else {
#pragma unroll 4
        for (int k = 0; k < H_; k += 32) {
          short8 af = *(const short8*)(Ap + k);
          short8 b0 = *(const short8*)(Bp0 + k);
          f0 = __builtin_amdgcn_mfma_f32_16x16x32_bf16(af, b0, f0, 0, 0, 0);
        }
      }
      if (col0 - vb < 40 && col0 < V_) {
        const float bs = b_fc[col0];
#pragma unroll
        for (int r = 0; r < 4; ++r) {
          int m = bf * 16 + quad * 4 + r;
          fc_out[(size_t)m * V_ + col0] = sigmoidf_(f0[r] + bs);
        }
      }
      if (two && col1 - vb < 40 && col1 < V_) {
        const float bs = b_fc[col1];
#pragma unroll
        for (int r = 0; r < 4; ++r) {
          int m = bf * 16 + quad * 4 + r;
          fc_out[(size_t)m * V_ + col1] = sigmoidf_(f1[r] + bs);
        }
      }
    }
  }
}

// ---------------------------------------------------------------------------
extern "C" void kernel_launch(void* const* d_in, const int* in_sizes, int n_in,
                              void* d_out, int out_size, void* d_ws, size_t ws_size,
                              hipStream_t stream) {
  const float* features    = (const float*)d_in[0];
  const int*   captions    = (const int*)d_in[1];
  const float* embed_table = (const float*)d_in[2];
  const float* W_init_h    = (const float*)d_in[3];
  const float* b_init_h    = (const float*)d_in[4];
  const float* W_init_c    = (const float*)d_in[5];
  const float* b_init_c    = (const float*)d_in[6];
  const float* W_ih        = (const float*)d_in[7];
  const float* b_ih        = (const float*)d_in[8];
  const float* W_hh        = (const float*)d_in[9];
  const float* b_hh        = (const float*)d_in[10];
  const float* W_fc        = (const float*)d_in[11];
  const float* b_fc        = (const float*)d_in[12];
  float* out = (float*)d_out;

  // ---- workspace carve-up (bump allocator, 256B aligned) ----
  char* ws = (char*)d_ws;
  auto alloc = [&](size_t bytes) -> char* {
    char* p = ws;
    ws += (bytes + 255) & ~(size_t)255;
    return p;
  };
  unsigned short* W_ih_b  = (unsigned short*)alloc((size_t)4 * H_ * E_ * 2);
  unsigned short* W_hh_b  = (unsigned short*)alloc((size_t)4 * H_ * H_ * 2);
  unsigned short* W_fc_b  = (unsigned short*)alloc((size_t)V_ * H_ * 2);
  // NOTE: Wih0_b and Wic0_b must stay CONTIGUOUS (fused [2H,F] init GEMM).
  unsigned short* Wih0_b  = (unsigned short*)alloc((size_t)H_ * F_ * 2);
  unsigned short* Wic0_b  = (unsigned short*)alloc((size_t)H_ * F_ * 2);
  unsigned short* feat_b  = (unsigned short*)alloc((size_t)B_ * F_ * 2);
  unsigned short* emb_b   = (unsigned short*)alloc((size_t)T_ * B_ * E_ * 2);
  unsigned short* gx_b    = (unsigned short*)alloc((size_t)T_ * B_ * 4 * H_ * 2);
  unsigned short* h_all   = (unsigned short*)alloc((size_t)(T_ + 1) * B_ * H_ * 2);
  float*          c_f32   = (float*)alloc((size_t)B_ * H_ * 4);
  (void)ws_size; (void)in_sizes; (void)n_in; (void)out_size; (void)Wic0_b;

  // ---- one fused fp32->bf16 conversion for all weights/features ----
  hipLaunchKernelGGL(cvt_all, dim3(4096), dim3(256), 0, stream,
                     W_ih, W_hh, W_fc, W_init_h, W_init_c, features,
                     W_ih_b, W_hh_b, W_fc_b, Wih0_b, Wic0_b, feat_b);

  hipLaunchKernelGGL(embed_gather, dim3(T_ * B_), dim3(128), 0, stream,
                     embed_table, captions, emb_b);

  // ---- fused h0|c0 init: one GEMM over N=2048 (Wih0_b||Wic0_b contiguous) -
  hipLaunchKernelGGL((mfma_gemm128<0, 1, 1>), dim3(1, 2 * H_ / 128), dim3(256), 0, stream,
                     feat_b, Wih0_b, b_init_h, b_init_c,
                     (void*)h_all, (void*)c_f32, B_, 2 * H_, F_);

  // ---- gx = emb @ W_ih^T + b_ih + b_hh for all t ----
  hipLaunchKernelGGL((mfma_gemm128<0, 1, 0>), dim3(T_ * B_ / 128, 4 * H_ / 128), dim3(256), 0, stream,
                     emb_b, W_ih_b, b_ih, b_hh, (void*)gx_b, (void*)nullptr,
                     T_ * B_, 4 * H_, E_);

  // ---- 32 sequential recurrent steps; launch t also computes the FC rows
  //      for its own input h_t (output time-row t-1) inside the same blocks -
  for (int t = 0; t < T_; ++t) {
    hipLaunchKernelGGL(lstm_step, dim3(H_ / 4), dim3(512), 0, stream,
                       W_hh_b,
                       gx_b + (size_t)t * B_ * 4 * H_,
                       c_f32,
                       h_all + (size_t)t * B_ * H_,
                       h_all + (size_t)(t + 1) * B_ * H_,
                       W_fc_b, b_fc,
                       (t == 0) ? (float*)nullptr : out + (size_t)(t - 1) * B_ * V_);
  }

  // ---- FC tail for h_32 (time-row 31): M=64 GEMM, 79 column blocks --------
  hipLaunchKernelGGL((mfma_gemm128<1, 0, 0>), dim3(1, (V_ + 127) / 128), dim3(256), 0, stream,
                     h_all + (size_t)T_ * B_ * H_, W_fc_b, b_fc, (const float*)nullptr,
                     (void*)(out + (size_t)(T_ - 1) * B_ * V_), (void*)nullptr,
                     B_, V_, H_);
}

// Round 3
// 503.328 us; speedup vs baseline: 2.2330x; 2.2330x over previous
//
#include <hip/hip_runtime.h>

// ---------------------------------------------------------------------------
// Decoder: fused cvt -> fused h0/c0 init GEMM -> gx GEMM -> 32 per-step
// LSTM launches -> one big FC GEMM (round-0 structure restored).
// Round-1 lesson: extra FC blocks serialize (step kernel is 1 block/CU).
// Round-2 lesson: in-block FC spills registers (128-VGPR cap) -- piggyback
// abandoned. New: step kernel reads h WITHOUT redundancy (64KB/block via
// 128 colgroups x 2 batch-halves x 4 K-quarter waves) -> 16MB/step vs 32MB.
// ---------------------------------------------------------------------------

#define B_  64
#define T_  32
#define E_  512
#define H_  1024
#define V_  10000
#define F_  2048

typedef short short8 __attribute__((ext_vector_type(8)));
typedef float floatx4 __attribute__((ext_vector_type(4)));

__device__ __forceinline__ float bf2f(unsigned short u) {
  union { unsigned int i; float f; } c; c.i = ((unsigned int)u) << 16; return c.f;
}
__device__ __forceinline__ unsigned short f2bf(float f) {
  union { float f; unsigned int i; } c; c.f = f;
  unsigned int x = c.i;
  return (unsigned short)((x + 0x7fffu + ((x >> 16) & 1u)) >> 16);
}
__device__ __forceinline__ float sigmoidf_(float x) {
  return 1.0f / (1.0f + __expf(-x));
}
// async global->LDS, 16B per lane. LDS dest = wave-uniform base + lane*16.
__device__ __forceinline__ void gl_lds16(const unsigned short* g, unsigned short* l) {
  __builtin_amdgcn_global_load_lds(
      (const __attribute__((address_space(1))) unsigned int*)g,
      (__attribute__((address_space(3))) unsigned int*)l, 16, 0, 0);
}
// bijective XCD-chunked block remap (m204 formula; identity when nwg < 8)
__device__ __forceinline__ int xcd_swz(int lin, int nwg) {
  if (nwg < 8) return lin;
  int q = nwg >> 3, r = nwg & 7;
  int xcd = lin & 7, pos = lin >> 3;
  return (xcd < r ? xcd * (q + 1) : r * (q + 1) + (xcd - r) * q) + pos;
}

// ---------------- fused fp32 -> bf16 convert for all 6 arrays --------------
#define C_WIH  524288    // 4H*E/4
#define C_WHH  1048576   // 4H*H/4
#define C_WFC  2560000   // V*H/4
#define C_WI0  524288    // H*F/4
#define C_WC0  524288
#define C_FEA  32768     // B*F/4
#define C_TOT  (C_WIH + C_WHH + C_WFC + C_WI0 + C_WC0 + C_FEA)

__global__ __launch_bounds__(256) void cvt_all(
    const float* __restrict__ s0, const float* __restrict__ s1,
    const float* __restrict__ s2, const float* __restrict__ s3,
    const float* __restrict__ s4, const float* __restrict__ s5,
    unsigned short* __restrict__ d0, unsigned short* __restrict__ d1,
    unsigned short* __restrict__ d2, unsigned short* __restrict__ d3,
    unsigned short* __restrict__ d4, unsigned short* __restrict__ d5) {
  int i = blockIdx.x * blockDim.x + threadIdx.x;
  int stride = gridDim.x * blockDim.x;
  for (; i < C_TOT; i += stride) {
    const float* s; unsigned short* d; int j = i;
    if (j < C_WIH)            { s = s0; d = d0; }
    else if ((j -= C_WIH) < C_WHH) { s = s1; d = d1; }
    else if ((j -= C_WHH) < C_WFC) { s = s2; d = d2; }
    else if ((j -= C_WFC) < C_WI0) { s = s3; d = d3; }
    else if ((j -= C_WI0) < C_WC0) { s = s4; d = d4; }
    else { j -= C_WC0; s = s5; d = d5; }
    float4 v = ((const float4*)s)[j];
    ushort4 o;
    o.x = f2bf(v.x); o.y = f2bf(v.y); o.z = f2bf(v.z); o.w = f2bf(v.w);
    ((ushort4*)d)[j] = o;
  }
}

// ---------------- embedding gather -> bf16, rows ordered (t*64+b) ----------
__global__ __launch_bounds__(128) void embed_gather(
    const float* __restrict__ table, const int* __restrict__ captions,
    unsigned short* __restrict__ out) {
  int row = blockIdx.x;            // row = t*B + b
  int t = row >> 6, b = row & 63;
  int idx = captions[b * T_ + t];
  const float4* src = (const float4*)(table + (size_t)idx * E_);
  ushort4* dst = (ushort4*)(out + (size_t)row * E_);
  for (int e = threadIdx.x; e < E_ / 4; e += blockDim.x) {
    float4 v = src[e];
    ushort4 o;
    o.x = f2bf(v.x); o.y = f2bf(v.y); o.z = f2bf(v.z); o.w = f2bf(v.w);
    dst[e] = o;
  }
}

// ---------------- 128x128 LDS-staged bf16 MFMA GEMM ------------------------
// C = act(A @ W^T + bias).  2-phase double-buffer: stage(next) issued before
// compute(cur); single barrier per K-iter (syncthreads drains vmcnt).
// XOR bank swizzle: LDS row of 32 shorts, 16B slot s holds global chunk
// s^(row&3) (global side permuted; LDS stays lane-linear for gl_lds).
// OUT_INIT: N=2048 fused h0|c0 -> out (bf16, stride H_) / out2 (f32).
template <int ACT_SIGMOID, int OUT_BF16, int OUT_INIT>
__global__ __launch_bounds__(256) void mfma_gemm128(
    const unsigned short* __restrict__ A, const unsigned short* __restrict__ W,
    const float* __restrict__ bias1, const float* __restrict__ bias2,
    void* __restrict__ out, void* __restrict__ out2, int M, int N, int K) {
  __shared__ unsigned short At[2][128 * 32];   // 16 KB
  __shared__ unsigned short Wt[2][128 * 32];   // 16 KB

  const int tid  = threadIdx.x;
  const int lane = tid & 63;
  const int wave = tid >> 6;
  const int l15  = lane & 15;
  const int quad = lane >> 4;
  const int wm   = (wave >> 1) * 64;
  const int wn   = (wave & 1) * 64;

  const int gx  = gridDim.x;
  const int nwg = gx * gridDim.y;
  const int wg  = xcd_swz(blockIdx.y * gx + blockIdx.x, nwg);
  const int m0  = (wg % gx) * 128;
  const int n0  = (wg / gx) * 128;
  const int ksl = (quad ^ (l15 & 3)) * 8;  // swizzled k-chunk for frag reads

  const int c0i = tid, c1i = tid + 256;
  const int ar0 = c0i >> 2, ak0 = (((c0i & 3) ^ (ar0 & 3)) * 8);
  const int ar1 = c1i >> 2, ak1 = (((c1i & 3) ^ (ar1 & 3)) * 8);
  int am0 = m0 + ar0; if (am0 > M - 1) am0 = M - 1;
  int am1 = m0 + ar1; if (am1 > M - 1) am1 = M - 1;
  int wn0 = n0 + ar0; if (wn0 > N - 1) wn0 = N - 1;
  int wn1 = n0 + ar1; if (wn1 > N - 1) wn1 = N - 1;
  const unsigned short* Ag0 = A + (size_t)am0 * K + ak0;
  const unsigned short* Ag1 = A + (size_t)am1 * K + ak1;
  const unsigned short* Wg0 = W + (size_t)wn0 * K + ak0;
  const unsigned short* Wg1 = W + (size_t)wn1 * K + ak1;

  floatx4 acc[4][4];
#pragma unroll
  for (int i = 0; i < 4; ++i)
#pragma unroll
    for (int j = 0; j < 4; ++j) acc[i][j] = (floatx4){0.f, 0.f, 0.f, 0.f};

  // prologue stage of k-tile 0 into buffer 0
  gl_lds16(Ag0, &At[0][c0i * 8]);
  gl_lds16(Ag1, &At[0][c1i * 8]);
  gl_lds16(Wg0, &Wt[0][c0i * 8]);
  gl_lds16(Wg1, &Wt[0][c1i * 8]);
  __syncthreads();

  int cur = 0;
  for (int k0 = 0; k0 < K; k0 += 32) {
    const int kn = k0 + 32;
    if (kn < K) {                      // issue next tile before compute
      const int nb = cur ^ 1;
      gl_lds16(Ag0 + kn, &At[nb][c0i * 8]);
      gl_lds16(Ag1 + kn, &At[nb][c1i * 8]);
      gl_lds16(Wg0 + kn, &Wt[nb][c0i * 8]);
      gl_lds16(Wg1 + kn, &Wt[nb][c1i * 8]);
    }
    short8 a[4], b[4];
#pragma unroll
    for (int mt = 0; mt < 4; ++mt)
      a[mt] = *(const short8*)&At[cur][(wm + mt * 16 + l15) * 32 + ksl];
#pragma unroll
    for (int nt = 0; nt < 4; ++nt)
      b[nt] = *(const short8*)&Wt[cur][(wn + nt * 16 + l15) * 32 + ksl];
#pragma unroll
    for (int mt = 0; mt < 4; ++mt)
#pragma unroll
      for (int nt = 0; nt < 4; ++nt)
        acc[mt][nt] = __builtin_amdgcn_mfma_f32_16x16x32_bf16(a[mt], b[nt], acc[mt][nt], 0, 0, 0);
    __syncthreads();                   // drains vmcnt: next tile resident
    cur ^= 1;
  }

#pragma unroll
  for (int nt = 0; nt < 4; ++nt) {
    int col = n0 + wn + nt * 16 + l15;
    if (col >= N) continue;
    float bsum;
    if (OUT_INIT)
      bsum = (col < H_) ? bias1[col] : bias2[col - H_];
    else
      bsum = (bias1 ? bias1[col] : 0.f) + (bias2 ? bias2[col] : 0.f);
#pragma unroll
    for (int mt = 0; mt < 4; ++mt) {
#pragma unroll
      for (int r = 0; r < 4; ++r) {
        int m = m0 + wm + mt * 16 + quad * 4 + r;
        if (m >= M) continue;
        float v = acc[mt][nt][r] + bsum;
        if (ACT_SIGMOID) v = sigmoidf_(v);
        if (OUT_INIT) {
          if (col < H_)
            ((unsigned short*)out)[(size_t)m * H_ + col] = f2bf(v);
          else
            ((float*)out2)[(size_t)m * H_ + (col - H_)] = v;
        } else if (OUT_BF16) {
          ((unsigned short*)out)[(size_t)m * N + col] = f2bf(v);
        } else {
          ((float*)out)[(size_t)m * N + col] = v;
        }
      }
    }
  }
}

// ---------------- per-step LSTM kernel (no-redundancy h reads) -------------
// Grid 256 blocks x 512 thr (1 block/CU). Block = (colgroup cg of 8 h-cols,
// batch-half bh of 32). 32 W_hh rows (gate-major n=g*8+j, 64KB) async-staged
// to LDS. Wave = (K-quarter kq 0..3, batch-frag mt 0..1): loads a DISJOINT
// 8KB h slice (hx[8], 32 VGPRs) -> block reads h exactly once (64KB);
// 16 MFMAs/wave in 2 ILP chains (rows 0-15 / 16-31). Partials reduced
// through gbuf[4 kq]. Total h traffic 16MB/step (was 32MB round-0).
#define WSPAD2 1032   // 1024 + 8 bf16 pad per row (granule spread)
__global__ __launch_bounds__(512, 2) void lstm_step(
    const unsigned short* __restrict__ W_hh_b,  // [4H,H] bf16
    const unsigned short* __restrict__ gx_t,    // [B,4H] bf16 (x-part+biases)
    float* __restrict__ c,                      // [B,H] f32, in-place
    const unsigned short* __restrict__ h_in,    // [B,H] bf16
    unsigned short* __restrict__ h_out) {       // [B,H] bf16
  __shared__ unsigned short Ws[32 * WSPAD2];    // ~64.5 KB
  __shared__ float gbuf[4][32][33];             // ~16.9 KB

  const int tid  = threadIdx.x;
  const int lane = tid & 63;
  const int wave = tid >> 6;        // 0..7
  const int l15  = lane & 15;
  const int quad = lane >> 4;
  const int kb   = quad * 8;
  const int cg   = blockIdx.x >> 1; // col-group: cols [cg*8, cg*8+8)
  const int bh   = blockIdx.x & 1;  // batch half: batches [bh*32, bh*32+32)
  const int colbase = cg * 8;
  const int kq   = wave >> 1;       // K quarter: [kq*256, kq*256+256)
  const int mt   = wave & 1;        // batch frag: bh*32 + mt*16 .. +16

  // ---- async-stage 32 W_hh rows (gate-major n=g*8+j) as 64 1KB units ------
#pragma unroll
  for (int it = 0; it < 8; ++it) {
    int u = wave * 8 + it;          // 0..63
    int n = u >> 1, half = u & 1;
    int grow = (n >> 3) * H_ + colbase + (n & 7);
    gl_lds16(W_hh_b + (size_t)grow * H_ + half * 512 + lane * 8,
             &Ws[n * WSPAD2 + half * 512]);
  }

  // ---- prefetch h slice (8 x 16B, disjoint per wave) ----------------------
  const unsigned short* hp =
      h_in + (size_t)(bh * 32 + mt * 16 + l15) * H_ + kq * 256 + kb;
  short8 hx[8];
#pragma unroll
  for (int i = 0; i < 8; ++i)
    hx[i] = *(const short8*)(hp + i * 32);

  // ---- prefetch cell inputs (waves 0-3 only; wave-uniform branch) ---------
  const int bq = tid >> 3, cj = tid & 7;   // batch-in-half, col-in-group
  float gxi = 0.f, gxf = 0.f, gxg = 0.f, gxo = 0.f, c_old = 0.f;
  if (tid < 256) {
    const int gb = bh * 32 + bq;
    const unsigned short* gxp = gx_t + (size_t)gb * (4 * H_) + colbase + cj;
    gxi = bf2f(gxp[0 * H_]);
    gxf = bf2f(gxp[1 * H_]);
    gxg = bf2f(gxp[2 * H_]);
    gxo = bf2f(gxp[3 * H_]);
    c_old = c[gb * H_ + colbase + cj];
  }

  __syncthreads();   // drains vmcnt: staging + prefetches complete

  // ---- 16 MFMAs: 8 k-chunks x 2 row-frags (ILP chains A0/A1) --------------
  const unsigned short* wb0 = &Ws[(size_t)(l15)      * WSPAD2 + kq * 256 + kb];
  const unsigned short* wb1 = &Ws[(size_t)(16 + l15) * WSPAD2 + kq * 256 + kb];
  floatx4 A0 = (floatx4){0.f, 0.f, 0.f, 0.f}, A1 = A0;
#pragma unroll
  for (int i = 0; i < 8; ++i) {
    short8 w0 = *(const short8*)(wb0 + i * 32);
    short8 w1 = *(const short8*)(wb1 + i * 32);
    A0 = __builtin_amdgcn_mfma_f32_16x16x32_bf16(hx[i], w0, A0, 0, 0, 0);
    A1 = __builtin_amdgcn_mfma_f32_16x16x32_bf16(hx[i], w1, A1, 0, 0, 0);
  }

#pragma unroll
  for (int r = 0; r < 4; ++r) {
    gbuf[kq][mt * 16 + quad * 4 + r][l15]      = A0[r];
    gbuf[kq][mt * 16 + quad * 4 + r][16 + l15] = A1[r];
  }
  __syncthreads();

  // ---- cell math: thread owns (batch bq in half, col colbase+cj) ----------
  if (tid < 256) {
    const int gb = bh * 32 + bq;
    float gi = gbuf[0][bq][ 0 + cj] + gbuf[1][bq][ 0 + cj]
             + gbuf[2][bq][ 0 + cj] + gbuf[3][bq][ 0 + cj] + gxi;
    float gf = gbuf[0][bq][ 8 + cj] + gbuf[1][bq][ 8 + cj]
             + gbuf[2][bq][ 8 + cj] + gbuf[3][bq][ 8 + cj] + gxf;
    float gg = gbuf[0][bq][16 + cj] + gbuf[1][bq][16 + cj]
             + gbuf[2][bq][16 + cj] + gbuf[3][bq][16 + cj] + gxg;
    float go = gbuf[0][bq][24 + cj] + gbuf[1][bq][24 + cj]
             + gbuf[2][bq][24 + cj] + gbuf[3][bq][24 + cj] + gxo;
    gi = sigmoidf_(gi);
    gf = sigmoidf_(gf);
    gg = tanhf(gg);
    go = sigmoidf_(go);
    int ci = gb * H_ + colbase + cj;
    float cn = gf * c_old + gi * gg;
    c[ci] = cn;
    h_out[ci] = f2bf(go * tanhf(cn));
  }
}

// ---------------------------------------------------------------------------
extern "C" void kernel_launch(void* const* d_in, const int* in_sizes, int n_in,
                              void* d_out, int out_size, void* d_ws, size_t ws_size,
                              hipStream_t stream) {
  const float* features    = (const float*)d_in[0];
  const int*   captions    = (const int*)d_in[1];
  const float* embed_table = (const float*)d_in[2];
  const float* W_init_h    = (const float*)d_in[3];
  const float* b_init_h    = (const float*)d_in[4];
  const float* W_init_c    = (const float*)d_in[5];
  const float* b_init_c    = (const float*)d_in[6];
  const float* W_ih        = (const float*)d_in[7];
  const float* b_ih        = (const float*)d_in[8];
  const float* W_hh        = (const float*)d_in[9];
  const float* b_hh        = (const float*)d_in[10];
  const float* W_fc        = (const float*)d_in[11];
  const float* b_fc        = (const float*)d_in[12];
  float* out = (float*)d_out;

  // ---- workspace carve-up (bump allocator, 256B aligned) ----
  char* ws = (char*)d_ws;
  auto alloc = [&](size_t bytes) -> char* {
    char* p = ws;
    ws += (bytes + 255) & ~(size_t)255;
    return p;
  };
  unsigned short* W_ih_b  = (unsigned short*)alloc((size_t)4 * H_ * E_ * 2);
  unsigned short* W_hh_b  = (unsigned short*)alloc((size_t)4 * H_ * H_ * 2);
  unsigned short* W_fc_b  = (unsigned short*)alloc((size_t)V_ * H_ * 2);
  // NOTE: Wih0_b and Wic0_b must stay CONTIGUOUS (fused [2H,F] init GEMM).
  unsigned short* Wih0_b  = (unsigned short*)alloc((size_t)H_ * F_ * 2);
  unsigned short* Wic0_b  = (unsigned short*)alloc((size_t)H_ * F_ * 2);
  unsigned short* feat_b  = (unsigned short*)alloc((size_t)B_ * F_ * 2);
  unsigned short* emb_b   = (unsigned short*)alloc((size_t)T_ * B_ * E_ * 2);
  unsigned short* gx_b    = (unsigned short*)alloc((size_t)T_ * B_ * 4 * H_ * 2);
  unsigned short* h_all   = (unsigned short*)alloc((size_t)(T_ + 1) * B_ * H_ * 2);
  float*          c_f32   = (float*)alloc((size_t)B_ * H_ * 4);
  (void)ws_size; (void)in_sizes; (void)n_in; (void)out_size; (void)Wic0_b;

  // ---- one fused fp32->bf16 conversion for all weights/features ----
  hipLaunchKernelGGL(cvt_all, dim3(4096), dim3(256), 0, stream,
                     W_ih, W_hh, W_fc, W_init_h, W_init_c, features,
                     W_ih_b, W_hh_b, W_fc_b, Wih0_b, Wic0_b, feat_b);

  hipLaunchKernelGGL(embed_gather, dim3(T_ * B_), dim3(128), 0, stream,
                     embed_table, captions, emb_b);

  // ---- fused h0|c0 init: one GEMM over N=2048 (Wih0_b||Wic0_b contiguous) -
  hipLaunchKernelGGL((mfma_gemm128<0, 1, 1>), dim3(1, 2 * H_ / 128), dim3(256), 0, stream,
                     feat_b, Wih0_b, b_init_h, b_init_c,
                     (void*)h_all, (void*)c_f32, B_, 2 * H_, F_);

  // ---- gx = emb @ W_ih^T + b_ih + b_hh for all t ----
  hipLaunchKernelGGL((mfma_gemm128<0, 1, 0>), dim3(T_ * B_ / 128, 4 * H_ / 128), dim3(256), 0, stream,
                     emb_b, W_ih_b, b_ih, b_hh, (void*)gx_b, (void*)nullptr,
                     T_ * B_, 4 * H_, E_);

  // ---- 32 sequential recurrent steps (256 blocks x 512 thr) ----
  for (int t = 0; t < T_; ++t) {
    hipLaunchKernelGGL(lstm_step, dim3(2 * H_ / 8), dim3(512), 0, stream,
                       W_hh_b,
                       gx_b + (size_t)t * B_ * 4 * H_,
                       c_f32,
                       h_all + (size_t)t * B_ * H_,
                       h_all + (size_t)(t + 1) * B_ * H_);
  }

  // ---- final FC: out = sigmoid(h_all[1..32] @ W_fc^T + b_fc) ----
  hipLaunchKernelGGL((mfma_gemm128<1, 0, 0>), dim3(T_ * B_ / 128, (V_ + 127) / 128), dim3(256), 0, stream,
                     h_all + (size_t)B_ * H_, W_fc_b, b_fc, (const float*)nullptr,
                     (void*)out, (void*)nullptr, T_ * B_, V_, H_);
}